// Round 6
// baseline (1749.985 us; speedup 1.0000x reference)
//
#include <hip/hip_runtime.h>

typedef __attribute__((ext_vector_type(8))) short short8;
typedef __attribute__((ext_vector_type(4))) float f32x4;

#define ACT_P 23384064ul       /* padded: sum(HpWp)*256*4n */
#define WSTEP 589824           /* 4 coq * 8 cc8 * 9 tap * 256 slot * 8 */

__device__ unsigned short g_actC[ACT_P];
__device__ unsigned short g_actA0[ACT_P];
__device__ unsigned short g_actB0[ACT_P];
__device__ unsigned short g_actA1[ACT_P];
__device__ unsigned short g_actB1[ACT_P];
__device__ unsigned short g_wc[4 * WSTEP];
__device__ unsigned short g_wr[4 * WSTEP];
__device__ unsigned short g_w1c[80 * 256];

__constant__ int      C_W[5]    = {128, 64, 32, 16, 8};
__constant__ int      C_WP[5]   = {130, 66, 34, 18, 10};
__constant__ int      C_HWP[5]  = {16900, 4356, 1156, 324, 100};
__constant__ int      C_LW[5]   = {7, 6, 5, 4, 3};
__constant__ int      C_LXT[5]  = {3, 2, 1, 0, 0};          // log2 of 16-px x-tiles
__constant__ int      C_PREF2[5]= {0, 256, 320, 336, 340};  // prefix of tiles*4coq
__constant__ int      C_HW[5]   = {16384, 4096, 1024, 256, 64};
__constant__ unsigned C_LOFFP[5]= {0u, 17305600u, 21766144u, 22949888u, 23281664u};
__constant__ unsigned C_CLSO[5] = {0u, 5242880u, 6553600u, 6881280u, 6963200u};
__constant__ unsigned C_REGO[5] = {6983680u, 7245824u, 7311360u, 7327744u, 7331840u};
__constant__ unsigned C_CENTO[5]= {7332864u, 7398400u, 7414784u, 7418880u, 7419904u};
__constant__ float    C_STRF[5] = {8.f, 16.f, 32.f, 64.f, 128.f};

static __device__ __forceinline__ unsigned short f2bf(float f) {
    unsigned u = __float_as_uint(f);
    unsigned r = (u + 0x7FFFu + ((u >> 16) & 1u)) >> 16;
    return (unsigned short)r;
}
static __device__ __forceinline__ float bf2f(unsigned short b) {
    return __uint_as_float(((unsigned)b) << 16);
}

// ---------------------------------------------------------------------------
// weight convert: (4,256,256,3,3) fp32 ->
//   [step][coq(4)][cc8(8)][tap(9)][g(4)][co64][ci8] bf16   (contiguous 36KB per chunk)
// grid: (256 co, 36 step*tap, 2 head), block 256 = ci
// ---------------------------------------------------------------------------
__global__ __launch_bounds__(256) void cvt_w3(
    const float* __restrict__ wc, const float* __restrict__ wr,
    unsigned short* __restrict__ oc, unsigned short* __restrict__ orr)
{
    const int co = blockIdx.x, sm = blockIdx.y, head = blockIdx.z;
    const int step = sm / 9, tap = sm - step * 9;
    const int ci = threadIdx.x;
    const float* w = head ? wr : wc;
    unsigned short* o = head ? orr : oc;
    const int coq = co >> 6, co64 = co & 63;
    const int cc8 = ci >> 5, g = (ci >> 3) & 3, e = ci & 7;
    o[(size_t)step * WSTEP +
      ((((size_t)(coq * 8 + cc8) * 9 + tap) * 256) + g * 64 + co64) * 8 + e] =
        f2bf(w[(((size_t)step * 256 + co) * 256 + ci) * 9 + tap]);
}

__global__ __launch_bounds__(256) void cvt_w1(
    const float* __restrict__ w, unsigned short* __restrict__ o)
{
    for (int idx = threadIdx.x; idx < 80 * 256; idx += 256)
        o[idx] = f2bf(w[idx]);
}

// ---------------------------------------------------------------------------
// zero the 1-px halo border of every level/n of all 5 padded buffers
// ---------------------------------------------------------------------------
__global__ __launch_bounds__(256) void zero_halo(
    unsigned short* c, unsigned short* a0, unsigned short* b0,
    unsigned short* a1, unsigned short* b1)
{
    unsigned short* bufs[5] = {c, a0, b0, a1, b1};
    const int bid = blockIdx.x;
    const int buf = bid / 20, r = bid - buf * 20, lvl = r >> 2, n = r & 3;
    const int Wp = C_WP[lvl], Hp = Wp;
    unsigned short* base = bufs[buf] + C_LOFFP[lvl] + (size_t)n * C_HWP[lvl] * 256;
    const int hc = 2 * Wp + 2 * (Hp - 2);
    uint4 z; z.x = z.y = z.z = z.w = 0u;
    for (int idx = threadIdx.x; idx < hc * 32; idx += 256) {
        int pos = idx >> 5, q = idx & 31;
        int row, col;
        if (pos < 2 * Wp) { row = (pos >= Wp) ? (Hp - 1) : 0; col = (pos >= Wp) ? pos - Wp : pos; }
        else { int rem = pos - 2 * Wp; row = 1 + (rem >> 1); col = (rem & 1) ? (Wp - 1) : 0; }
        *(uint4*)(base + ((size_t)(row * Wp + col) << 8) + q * 8) = z;
    }
}

// ---------------------------------------------------------------------------
// input convert: fp32 NCHW -> bf16 padded NHWC.
// ---------------------------------------------------------------------------
__global__ __launch_bounds__(256) void cvt_in(
    const float* __restrict__ f0, const float* __restrict__ f1,
    const float* __restrict__ f2, const float* __restrict__ f3,
    const float* __restrict__ f4, unsigned short* __restrict__ dstC)
{
    const int lvl = blockIdx.y, n = blockIdx.z;
    const int HW = C_HW[lvl];
    const int p0 = blockIdx.x * 64;
    if (p0 >= HW) return;
    const int W = C_W[lvl], lw = C_LW[lvl], Wp = C_WP[lvl];
    const float* fp[5] = {f0, f1, f2, f3, f4};
    const float* src = fp[lvl] + (size_t)n * 256 * HW;
    unsigned short* dst = dstC + C_LOFFP[lvl] + (size_t)n * C_HWP[lvl] * 256;
    const int tid = threadIdx.x;
    __shared__ float ts[64][65];

    for (int cc = 0; cc < 256; cc += 64) {
        for (int idx = tid; idx < 64 * 64; idx += 256) {
            int ci = idx >> 6, p = idx & 63;
            ts[ci][p] = src[(size_t)(cc + ci) * HW + p0 + p];
        }
        __syncthreads();
        for (int idx = tid; idx < 64 * 64; idx += 256) {
            int p = idx >> 6, ci = idx & 63;
            int gp = p0 + p, y = gp >> lw, x = gp & (W - 1);
            dst[(size_t)((y + 1) * Wp + x + 1) * 256 + cc + ci] = f2bf(ts[ci][p]);
        }
        __syncthreads();
    }
}

// ---------------------------------------------------------------------------
// 3x3 conv + BN + ReLU, bf16 MFMA implicit GEMM.
// Block = 64 co x 256 px (16y x 16x), 4 waves (wave 64co x 64px, 4mf x 4nf).
// Per 32-ci chunk: A (9 tap x 32 ci x 64 co) -> LDS via global_load_lds w16;
// B (18y x 19x halo tile) -> LDS via register path, prefetched under MFMA.
// grid: (344 packed tile*coq, 1, 8 = head*4+n), block 256.
// ---------------------------------------------------------------------------
__global__ __launch_bounds__(256, 2) void conv3x3_mfma(
    const unsigned short* __restrict__ src0, const unsigned short* __restrict__ src1,
    unsigned short* __restrict__ dst0, unsigned short* __restrict__ dst1,
    const unsigned short* __restrict__ wt0, const unsigned short* __restrict__ wt1,
    const float* __restrict__ sc0, const float* __restrict__ bi0,
    const float* __restrict__ sc1, const float* __restrict__ bi1)
{
    int tc = blockIdx.x;
    const int lvl = (tc >= 256) + (tc >= 320) + (tc >= 336) + (tc >= 340);
    tc -= C_PREF2[lvl];
    const int head = blockIdx.z >> 2, n = blockIdx.z & 3;

    const int W = C_W[lvl], H = W, Wp = C_WP[lvl];
    const int lxt = C_LXT[lvl];
    const int coq = tc & 3, tile = tc >> 2;
    const int tx = tile & ((1 << lxt) - 1), ty = tile >> lxt;
    const int x0 = tx * 16, y0 = ty * 16;

    const unsigned short* src = head ? src1 : src0;
    unsigned short*       dst = head ? dst1 : dst0;
    const unsigned short* wt  = head ? wt1 : wt0;
    const float* sc = head ? sc1 : sc0;
    const float* bi = head ? bi1 : bi0;
    const size_t actOff = (size_t)C_LOFFP[lvl] + (size_t)n * C_HWP[lvl] * 256;
    src += actOff; dst += actOff;
    const unsigned short* wtc = wt + (size_t)coq * 147456;   // 8*9*256*8

    const int tid = threadIdx.x;
    const int lane = tid & 63, wid = tid >> 6;
    const int l16 = lane & 15, quad = lane >> 4;
    const int jw = wid * 4;                                  // wave x base (LDS-local)

    // A: [tap(9)][g(4)][co(65 pad)] x 16B = 37440 B ; B: [g(4)][x(19)][y(18)] x 16B = 21888 B
    __shared__ unsigned short A_s[9 * 4 * 65 * 8];
    __shared__ unsigned short B_s[4 * 19 * 18 * 8];
    char* Ab = (char*)A_s;
    char* Bb = (char*)B_s;

    // ---- B staging slots: 6 per thread (1536 issued, 1368 real, clamped) ----
    int bgo[6], bls[6];
#pragma unroll
    for (int it = 0; it < 6; it++) {
        int slot = tid + it * 256;
        if (slot > 1367) slot = 1367;
        int g = (slot * 24529) >> 23;        // /342
        int r = slot - g * 342;
        int x = (r * 3641) >> 16;            // /18 (x up to 18 = pad col)
        int y = r - x * 18;
        int gxp = x0 + x; if (gxp > Wp - 1) gxp = Wp - 1;
        int gyp = y0 + y; if (gyp > Wp - 1) gyp = Wp - 1;
        bgo[it] = ((gyp * Wp + gxp) << 8) + g * 8;
        bls[it] = slot;
    }

    f32x4 acc[4][4];
#pragma unroll
    for (int mf = 0; mf < 4; mf++)
#pragma unroll
        for (int nf = 0; nf < 4; nf++) acc[mf][nf] = (f32x4){0.f, 0.f, 0.f, 0.f};

    // ---- prologue: load B chunk 0 into regs ----
    uint4 bv[6];
#pragma unroll
    for (int it = 0; it < 6; it++) bv[it] = *(const uint4*)(src + bgo[it]);

    for (int c8 = 0; c8 < 8; c8++) {
        __syncthreads();
        // ---- A: async DMA this chunk's 36KB slab into LDS (9 calls/wave) ----
        const unsigned short* wch = wtc + c8 * 18432;
#pragma unroll
        for (int it = 0; it < 9; it++) {
            const int sb = (wid * 9 + it) * 64;
            const int tap = sb >> 8, g = (sb >> 6) & 3;
            __builtin_amdgcn_global_load_lds(
                (const __attribute__((address_space(1))) unsigned int*)(const void*)(wch + (sb + lane) * 8),
                (__attribute__((address_space(3))) unsigned int*)(void*)(Ab + ((tap * 4 + g) * 65) * 16),
                16, 0, 0);
        }
        // ---- B: write staged regs ----
#pragma unroll
        for (int it = 0; it < 6; it++) *(uint4*)(Bb + bls[it] * 16) = bv[it];
        __syncthreads();

        // ---- prefetch next chunk's B (latency hides under own MFMA) ----
        if (c8 < 7) {
            const int cco = (c8 + 1) * 32;
#pragma unroll
            for (int it = 0; it < 6; it++)
                bv[it] = *(const uint4*)(src + bgo[it] + cco);
        }

        // ---- MFMA phase ----
#pragma unroll
        for (int kh = 0; kh < 3; kh++) {
            short8 Bf[6];
#pragma unroll
            for (int j = 0; j < 6; j++)
                Bf[j] = *(const short8*)(Bb + (quad * 342 + (jw + j) * 18 + l16 + kh) * 16);
#pragma unroll
            for (int kw = 0; kw < 3; kw++) {
                const int tap = kh * 3 + kw;
                short8 Af[4];
#pragma unroll
                for (int mf = 0; mf < 4; mf++)
                    Af[mf] = *(const short8*)(Ab + ((tap * 4 + quad) * 65 + mf * 16 + l16) * 16);
#pragma unroll
                for (int nf = 0; nf < 4; nf++)
#pragma unroll
                    for (int mf = 0; mf < 4; mf++)
                        acc[mf][nf] = __builtin_amdgcn_mfma_f32_16x16x32_bf16(
                            Af[mf], Bf[nf + kw], acc[mf][nf], 0, 0, 0);
            }
        }
    }

    // ---- epilogue: BN + ReLU + cvt bf16, padded NHWC store ----
    const int gy = y0 + l16;
    if (gy < H) {
#pragma unroll
        for (int mf = 0; mf < 4; mf++) {
            const int co4 = coq * 64 + mf * 16 + quad * 4;
            const f32x4 s4 = *(const f32x4*)(sc + co4);
            const f32x4 b4 = *(const f32x4*)(bi + co4);
#pragma unroll
            for (int nf = 0; nf < 4; nf++) {
                const int gx = x0 + jw + nf;
                if (gx < W) {
                    f32x4 v = acc[mf][nf];
                    ushort4 o;
                    o.x = f2bf(fmaxf(v[0] * s4[0] + b4[0], 0.f));
                    o.y = f2bf(fmaxf(v[1] * s4[1] + b4[1], 0.f));
                    o.z = f2bf(fmaxf(v[2] * s4[2] + b4[2], 0.f));
                    o.w = f2bf(fmaxf(v[3] * s4[3] + b4[3], 0.f));
                    *(ushort4*)(dst + ((size_t)((gy + 1) * Wp + gx + 1) * 256 + co4)) = o;
                }
            }
        }
    }
}

// ---------------------------------------------------------------------------
// final 1x1 cls: 256 -> 80 + bias, MFMA, fp32 NCHW out (padded NHWC input).
// ---------------------------------------------------------------------------
__global__ __launch_bounds__(256) void final_cls(
    const unsigned short* __restrict__ act, const unsigned short* __restrict__ w,
    const float* __restrict__ bias, float* __restrict__ out)
{
    const int lvl = blockIdx.y, n = blockIdx.z;
    const int HW = C_HW[lvl];
    const int p0 = blockIdx.x * 128;
    if (p0 >= HW) return;
    const int W = C_W[lvl], lw = C_LW[lvl], Wp = C_WP[lvl];

    const int tid = threadIdx.x;
    const int lane = tid & 63, wid = tid >> 6;
    const int l16 = lane & 15, quad = lane >> 4;

    const unsigned short* a = act + C_LOFFP[lvl] + (size_t)n * C_HWP[lvl] * 256;

    int px[2]; size_t aoff[2];
#pragma unroll
    for (int j = 0; j < 2; j++) {
        px[j] = p0 + wid * 32 + j * 16 + l16;
        int lpx = px[j] < HW ? px[j] : 0;
        int y = lpx >> lw, x = lpx & (W - 1);
        aoff[j] = (size_t)((y + 1) * Wp + x + 1) * 256;
    }

    f32x4 acc[5][2];
#pragma unroll
    for (int mf = 0; mf < 5; mf++) { acc[mf][0] = (f32x4){0,0,0,0}; acc[mf][1] = (f32x4){0,0,0,0}; }

    for (int cc = 0; cc < 256; cc += 32) {
        short8 b0 = *(const short8*)(a + aoff[0] + cc + quad * 8);
        short8 b1 = *(const short8*)(a + aoff[1] + cc + quad * 8);
#pragma unroll
        for (int mf = 0; mf < 5; mf++) {
            short8 av = *(const short8*)(w + (mf * 16 + l16) * 256 + cc + quad * 8);
            acc[mf][0] = __builtin_amdgcn_mfma_f32_16x16x32_bf16(av, b0, acc[mf][0], 0, 0, 0);
            acc[mf][1] = __builtin_amdgcn_mfma_f32_16x16x32_bf16(av, b1, acc[mf][1], 0, 0, 0);
        }
    }

    float* ob = out + C_CLSO[lvl] + (size_t)n * 80 * HW;
#pragma unroll
    for (int mf = 0; mf < 5; mf++) {
        const int co0 = mf * 16 + quad * 4;
#pragma unroll
        for (int j = 0; j < 2; j++) {
            if (px[j] < HW) {
#pragma unroll
                for (int r = 0; r < 4; r++)
                    ob[(size_t)(co0 + r) * HW + px[j]] = acc[mf][j][r] + bias[co0 + r];
            }
        }
    }
}

// ---------------------------------------------------------------------------
// final 1x1 reg: 256 -> 5 + bias; ch0 centerness, ch1..4 max(raw*stride,0).
// ---------------------------------------------------------------------------
__global__ __launch_bounds__(256) void final_reg(
    const unsigned short* __restrict__ act, const float* __restrict__ w,
    const float* __restrict__ bias, float* __restrict__ out)
{
    const int lvl = blockIdx.y, n = blockIdx.z;
    const int HW = C_HW[lvl];
    const int W = C_W[lvl], lw = C_LW[lvl], Wp = C_WP[lvl];
    const int tid = threadIdx.x;

    __shared__ float ws[5 * 256];
    for (int idx = tid; idx < 5 * 256; idx += 256) ws[idx] = w[idx];
    __syncthreads();

    const int px = blockIdx.x * 256 + tid;
    if (px >= HW) return;

    const int y = px >> lw, x = px & (W - 1);
    const unsigned short* a = act + C_LOFFP[lvl] + (size_t)n * C_HWP[lvl] * 256
                            + (size_t)((y + 1) * Wp + x + 1) * 256;
    float acc[5] = {0.f, 0.f, 0.f, 0.f, 0.f};

    for (int ci = 0; ci < 256; ci += 8) {
        ushort4 u0 = *(const ushort4*)(a + ci);
        ushort4 u1 = *(const ushort4*)(a + ci + 4);
        float xv[8] = {bf2f(u0.x), bf2f(u0.y), bf2f(u0.z), bf2f(u0.w),
                       bf2f(u1.x), bf2f(u1.y), bf2f(u1.z), bf2f(u1.w)};
#pragma unroll
        for (int j = 0; j < 5; j++) {
            const float* wj = &ws[j * 256 + ci];
#pragma unroll
            for (int k = 0; k < 8; k++) acc[j] = fmaf(xv[k], wj[k], acc[j]);
        }
    }

    const float strf = C_STRF[lvl];
    out[C_CENTO[lvl] + (size_t)n * HW + px] = acc[0] + bias[0];
    float* rb = out + C_REGO[lvl] + (size_t)n * 4 * HW;
#pragma unroll
    for (int j = 0; j < 4; j++)
        rb[(size_t)j * HW + px] = fmaxf((acc[j + 1] + bias[j + 1]) * strf, 0.f);
}

// ---------------------------------------------------------------------------
extern "C" void kernel_launch(void* const* d_in, const int* in_sizes, int n_in,
                              void* d_out, int out_size, void* d_ws, size_t ws_size,
                              hipStream_t stream)
{
    const float* cls_w  = (const float*)d_in[5];
    const float* cls_s  = (const float*)d_in[6];
    const float* cls_b  = (const float*)d_in[7];
    const float* cls_fw = (const float*)d_in[8];
    const float* cls_fb = (const float*)d_in[9];
    const float* reg_w  = (const float*)d_in[10];
    const float* reg_s  = (const float*)d_in[11];
    const float* reg_b  = (const float*)d_in[12];
    const float* reg_fw = (const float*)d_in[13];
    const float* reg_fb = (const float*)d_in[14];
    float* out = (float*)d_out;

    unsigned short *actC, *actA0, *actB0, *actA1, *actB1, *wc, *wr, *w1c;
    hipGetSymbolAddress((void**)&actC,  HIP_SYMBOL(g_actC));
    hipGetSymbolAddress((void**)&actA0, HIP_SYMBOL(g_actA0));
    hipGetSymbolAddress((void**)&actB0, HIP_SYMBOL(g_actB0));
    hipGetSymbolAddress((void**)&actA1, HIP_SYMBOL(g_actA1));
    hipGetSymbolAddress((void**)&actB1, HIP_SYMBOL(g_actB1));
    hipGetSymbolAddress((void**)&wc,    HIP_SYMBOL(g_wc));
    hipGetSymbolAddress((void**)&wr,    HIP_SYMBOL(g_wr));
    hipGetSymbolAddress((void**)&w1c,   HIP_SYMBOL(g_w1c));

    cvt_w3<<<dim3(256, 36, 2), 256, 0, stream>>>(cls_w, reg_w, wc, wr);
    cvt_w1<<<1, 256, 0, stream>>>(cls_fw, w1c);
    zero_halo<<<100, 256, 0, stream>>>(actC, actA0, actB0, actA1, actB1);
    cvt_in<<<dim3(256, 5, 4), 256, 0, stream>>>(
        (const float*)d_in[0], (const float*)d_in[1], (const float*)d_in[2],
        (const float*)d_in[3], (const float*)d_in[4], actC);

    unsigned short* srcs[4][2] = {{actC, actC}, {actA0, actA1}, {actB0, actB1}, {actA0, actA1}};
    unsigned short* dsts[4][2] = {{actA0, actA1}, {actB0, actB1}, {actA0, actA1}, {actB0, actB1}};
    for (int s = 0; s < 4; s++) {
        conv3x3_mfma<<<dim3(344, 1, 8), 256, 0, stream>>>(
            srcs[s][0], srcs[s][1], dsts[s][0], dsts[s][1],
            wc + (size_t)s * WSTEP, wr + (size_t)s * WSTEP,
            cls_s + s * 256, cls_b + s * 256, reg_s + s * 256, reg_b + s * 256);
    }

    final_cls<<<dim3(128, 5, 4), 256, 0, stream>>>(actB0, w1c, cls_fb, out);
    final_reg<<<dim3(64, 5, 4), 256, 0, stream>>>(actB1, reg_fw, reg_fb, out);
}

// Round 7
// 1213.255 us; speedup vs baseline: 1.4424x; 1.4424x over previous
//
#include <hip/hip_runtime.h>

typedef __attribute__((ext_vector_type(8))) short short8;
typedef __attribute__((ext_vector_type(4))) float f32x4;

#define ACT_P 23384064ul       /* padded: sum(HpWp)*256*4n */
#define WSTEP 589824           /* 9 tap * 32 ci8 * 256 co * 8 */

__device__ unsigned short g_actC[ACT_P];
__device__ unsigned short g_actA0[ACT_P];
__device__ unsigned short g_actB0[ACT_P];
__device__ unsigned short g_actA1[ACT_P];
__device__ unsigned short g_actB1[ACT_P];
__device__ unsigned short g_wc[4 * WSTEP];
__device__ unsigned short g_wr[4 * WSTEP];
__device__ unsigned short g_w1c[80 * 256];

__constant__ int      C_W[5]    = {128, 64, 32, 16, 8};
__constant__ int      C_WP[5]   = {130, 66, 34, 18, 10};
__constant__ int      C_HWP[5]  = {16900, 4356, 1156, 324, 100};
__constant__ int      C_LW[5]   = {7, 6, 5, 4, 3};
__constant__ int      C_LXT[5]  = {4, 3, 2, 1, 0};          // log2(W/8 x-tiles)
__constant__ int      C_PREF[5] = {0, 128, 160, 168, 170};  // tile prefix (171 total)
__constant__ int      C_HW[5]   = {16384, 4096, 1024, 256, 64};
__constant__ unsigned C_LOFFP[5]= {0u, 17305600u, 21766144u, 22949888u, 23281664u};
__constant__ unsigned C_CLSO[5] = {0u, 5242880u, 6553600u, 6881280u, 6963200u};
__constant__ unsigned C_REGO[5] = {6983680u, 7245824u, 7311360u, 7327744u, 7331840u};
__constant__ unsigned C_CENTO[5]= {7332864u, 7398400u, 7414784u, 7418880u, 7419904u};
__constant__ float    C_STRF[5] = {8.f, 16.f, 32.f, 64.f, 128.f};

static __device__ __forceinline__ unsigned short f2bf(float f) {
    unsigned u = __float_as_uint(f);
    unsigned r = (u + 0x7FFFu + ((u >> 16) & 1u)) >> 16;
    return (unsigned short)r;
}
static __device__ __forceinline__ float bf2f(unsigned short b) {
    return __uint_as_float(((unsigned)b) << 16);
}

// ---------------------------------------------------------------------------
// weight convert: (4,256,256,3,3) fp32 -> [step][tap(9)][ci8(32)][co(256)][8] bf16
// grid: (256 co, 36 step*tap, 2 head), block 256 = ci
// ---------------------------------------------------------------------------
__global__ __launch_bounds__(256) void cvt_w3(
    const float* __restrict__ wc, const float* __restrict__ wr,
    unsigned short* __restrict__ oc, unsigned short* __restrict__ orr)
{
    const int co = blockIdx.x, sm = blockIdx.y, head = blockIdx.z;
    const int step = sm / 9, tap = sm - step * 9;
    const int ci = threadIdx.x;
    const float* w = head ? wr : wc;
    unsigned short* o = head ? orr : oc;
    o[(((size_t)sm * 32 + (ci >> 3)) * 256 + co) * 8 + (ci & 7)] =
        f2bf(w[(((size_t)step * 256 + co) * 256 + ci) * 9 + tap]);
}

__global__ __launch_bounds__(256) void cvt_w1(
    const float* __restrict__ w, unsigned short* __restrict__ o)
{
    for (int idx = threadIdx.x; idx < 80 * 256; idx += 256)
        o[idx] = f2bf(w[idx]);
}

// ---------------------------------------------------------------------------
// zero the 1-px halo border of every level/n of all 5 padded buffers
// ---------------------------------------------------------------------------
__global__ __launch_bounds__(256) void zero_halo(
    unsigned short* c, unsigned short* a0, unsigned short* b0,
    unsigned short* a1, unsigned short* b1)
{
    unsigned short* bufs[5] = {c, a0, b0, a1, b1};
    const int bid = blockIdx.x;
    const int buf = bid / 20, r = bid - buf * 20, lvl = r >> 2, n = r & 3;
    const int Wp = C_WP[lvl], Hp = Wp;
    unsigned short* base = bufs[buf] + C_LOFFP[lvl] + (size_t)n * C_HWP[lvl] * 256;
    const int hc = 2 * Wp + 2 * (Hp - 2);
    uint4 z; z.x = z.y = z.z = z.w = 0u;
    for (int idx = threadIdx.x; idx < hc * 32; idx += 256) {
        int pos = idx >> 5, q = idx & 31;
        int row, col;
        if (pos < 2 * Wp) { row = (pos >= Wp) ? (Hp - 1) : 0; col = (pos >= Wp) ? pos - Wp : pos; }
        else { int rem = pos - 2 * Wp; row = 1 + (rem >> 1); col = (rem & 1) ? (Wp - 1) : 0; }
        *(uint4*)(base + ((size_t)(row * Wp + col) << 8) + q * 8) = z;
    }
}

// ---------------------------------------------------------------------------
// input convert: fp32 NCHW -> bf16 padded NHWC.
// ---------------------------------------------------------------------------
__global__ __launch_bounds__(256) void cvt_in(
    const float* __restrict__ f0, const float* __restrict__ f1,
    const float* __restrict__ f2, const float* __restrict__ f3,
    const float* __restrict__ f4, unsigned short* __restrict__ dstC)
{
    const int lvl = blockIdx.y, n = blockIdx.z;
    const int HW = C_HW[lvl];
    const int p0 = blockIdx.x * 64;
    if (p0 >= HW) return;
    const int W = C_W[lvl], lw = C_LW[lvl], Wp = C_WP[lvl];
    const float* fp[5] = {f0, f1, f2, f3, f4};
    const float* src = fp[lvl] + (size_t)n * 256 * HW;
    unsigned short* dst = dstC + C_LOFFP[lvl] + (size_t)n * C_HWP[lvl] * 256;
    const int tid = threadIdx.x;
    __shared__ float ts[64][65];

    for (int cc = 0; cc < 256; cc += 64) {
        for (int idx = tid; idx < 64 * 64; idx += 256) {
            int ci = idx >> 6, p = idx & 63;
            ts[ci][p] = src[(size_t)(cc + ci) * HW + p0 + p];
        }
        __syncthreads();
        for (int idx = tid; idx < 64 * 64; idx += 256) {
            int p = idx >> 6, ci = idx & 63;
            int gp = p0 + p, y = gp >> lw, x = gp & (W - 1);
            dst[(size_t)((y + 1) * Wp + x + 1) * 256 + cc + ci] = f2bf(ts[ci][p]);
        }
        __syncthreads();
    }
}

// ---------------------------------------------------------------------------
// 3x3 conv + BN + ReLU, bf16 MFMA implicit GEMM.
// Block = 512 thr = 8 waves (4 coq x 2 xh): tile 256 co x 128 px (16y x 8x).
// Wave = 64 co x 64 px (16y x 4x), acc 4x4 f32x4.
// B: FULL 256-ci halo tile (18y x 10x) staged once into 95KB LDS in two
// halves; half-1 loads issued before ph-0 compute (in flight across the
// single mid-loop barrier).  K-loop itself is barrier-free; A streams from
// L2 per tap.  LDS layout [g(32)][x(10)][y(19 pad)] x 16B -> conflict-free
// b128 reads, 2-way (free) y aliasing.
// grid: (171 packed tiles, 1, 8 = head*4+n).
// ---------------------------------------------------------------------------
__global__ __launch_bounds__(512, 2) void conv3x3_mfma(
    const unsigned short* __restrict__ src0, const unsigned short* __restrict__ src1,
    unsigned short* __restrict__ dst0, unsigned short* __restrict__ dst1,
    const unsigned short* __restrict__ wt0, const unsigned short* __restrict__ wt1,
    const float* __restrict__ sc0, const float* __restrict__ bi0,
    const float* __restrict__ sc1, const float* __restrict__ bi1)
{
    int tc = blockIdx.x;
    const int lvl = (tc >= 128) + (tc >= 160) + (tc >= 168) + (tc >= 170);
    tc -= C_PREF[lvl];
    const int head = blockIdx.z >> 2, n = blockIdx.z & 3;

    const int W = C_W[lvl], H = W, Wp = C_WP[lvl];
    const int lxt = C_LXT[lvl];
    const int tx = tc & ((1 << lxt) - 1), ty = tc >> lxt;
    const int x0 = tx * 8, y0 = ty * 16;

    const unsigned short* src = head ? src1 : src0;
    unsigned short*       dst = head ? dst1 : dst0;
    const unsigned short* wt  = head ? wt1 : wt0;
    const float* sc = head ? sc1 : sc0;
    const float* bi = head ? bi1 : bi0;
    const size_t actOff = (size_t)C_LOFFP[lvl] + (size_t)n * C_HWP[lvl] * 256;
    src += actOff; dst += actOff;

    const int tid = threadIdx.x;
    const int lane = tid & 63, wid = tid >> 6;
    const int l16 = lane & 15, quad = lane >> 4;
    const int coq = wid & 3, xh = wid >> 2;
    const int cow = coq * 64, jw = xh * 4;

    // LDS: [g(32)][x(10)][y(19)] x 16B = 97280 B
    __shared__ unsigned short B_s[32 * 10 * 19 * 8];
    char* Bb = (char*)B_s;

    // ---- staging addresses: half-0 = g 0..15 (ci 0..127); 2880 slots ----
    int goff[6], ldso[6];
#pragma unroll
    for (int it = 0; it < 6; it++) {
        int slot = tid + it * 512;
        if (slot > 2879) slot = 2879;
        int g = slot & 15, p = slot >> 4;       // p = y*10 + x, p < 180
        int y = (p * 205) >> 11;                // /10
        int x = p - y * 10;
        int gyp = y0 + y; if (gyp > Wp - 1) gyp = Wp - 1;   // lvl4 clamps to zero halo row
        goff[it] = (((gyp * Wp) + x0 + x) << 8) + g * 8;
        ldso[it] = ((g * 10 + x) * 19 + y) * 16;
    }

    f32x4 acc[4][4];
#pragma unroll
    for (int mf = 0; mf < 4; mf++)
#pragma unroll
        for (int nf = 0; nf < 4; nf++) acc[mf][nf] = (f32x4){0.f, 0.f, 0.f, 0.f};

    // ---- stage half-0 ----
    uint4 bv[6];
#pragma unroll
    for (int it = 0; it < 6; it++) bv[it] = *(const uint4*)(src + goff[it]);
#pragma unroll
    for (int it = 0; it < 6; it++) *(uint4*)(Bb + ldso[it]) = bv[it];
    __syncthreads();
    // ---- issue half-1 loads NOW (in flight across ph-0 compute) ----
#pragma unroll
    for (int it = 0; it < 6; it++) bv[it] = *(const uint4*)(src + goff[it] + 128);

#pragma unroll
    for (int ph = 0; ph < 2; ph++) {
        if (ph == 1) {
            // write half-1 (g 16..31) and sync once; loads long since landed
#pragma unroll
            for (int it = 0; it < 6; it++) *(uint4*)(Bb + ldso[it] + 48640) = bv[it];
            __syncthreads();
        }
#pragma unroll
        for (int c4 = 0; c4 < 4; c4++) {
            const int c32 = ph * 4 + c4;
#pragma unroll
            for (int kh = 0; kh < 3; kh++) {
                short8 Bf[6];
#pragma unroll
                for (int j = 0; j < 6; j++)
                    Bf[j] = *(const short8*)(Bb +
                        (((c32 * 4 + quad) * 10 + jw + j) * 19 + l16 + kh) * 16);
#pragma unroll
                for (int kw = 0; kw < 3; kw++) {
                    const int tap = kh * 3 + kw;
                    short8 Af[4];
#pragma unroll
                    for (int mf = 0; mf < 4; mf++)
                        Af[mf] = *(const short8*)(wt +
                            (((tap * 32 + c32 * 4 + quad) * 256) + cow + mf * 16 + l16) * 8);
#pragma unroll
                    for (int nf = 0; nf < 4; nf++)
#pragma unroll
                        for (int mf = 0; mf < 4; mf++)
                            acc[mf][nf] = __builtin_amdgcn_mfma_f32_16x16x32_bf16(
                                Af[mf], Bf[nf + kw], acc[mf][nf], 0, 0, 0);
                }
            }
        }
    }

    // ---- epilogue: BN + ReLU + cvt bf16, padded NHWC store ----
    const int gy = y0 + l16;
    if (gy < H) {
#pragma unroll
        for (int mf = 0; mf < 4; mf++) {
            const int co4 = cow + mf * 16 + quad * 4;
            const f32x4 s4 = *(const f32x4*)(sc + co4);
            const f32x4 b4 = *(const f32x4*)(bi + co4);
#pragma unroll
            for (int nf = 0; nf < 4; nf++) {
                const int gx = x0 + jw + nf;
                f32x4 v = acc[mf][nf];
                ushort4 o;
                o.x = f2bf(fmaxf(v[0] * s4[0] + b4[0], 0.f));
                o.y = f2bf(fmaxf(v[1] * s4[1] + b4[1], 0.f));
                o.z = f2bf(fmaxf(v[2] * s4[2] + b4[2], 0.f));
                o.w = f2bf(fmaxf(v[3] * s4[3] + b4[3], 0.f));
                *(ushort4*)(dst + ((size_t)((gy + 1) * Wp + gx + 1) * 256 + co4)) = o;
            }
        }
    }
}

// ---------------------------------------------------------------------------
// final 1x1 cls: 256 -> 80 + bias, MFMA, fp32 NCHW out (padded NHWC input).
// ---------------------------------------------------------------------------
__global__ __launch_bounds__(256) void final_cls(
    const unsigned short* __restrict__ act, const unsigned short* __restrict__ w,
    const float* __restrict__ bias, float* __restrict__ out)
{
    const int lvl = blockIdx.y, n = blockIdx.z;
    const int HW = C_HW[lvl];
    const int p0 = blockIdx.x * 128;
    if (p0 >= HW) return;
    const int W = C_W[lvl], lw = C_LW[lvl], Wp = C_WP[lvl];

    const int tid = threadIdx.x;
    const int lane = tid & 63, wid = tid >> 6;
    const int l16 = lane & 15, quad = lane >> 4;

    const unsigned short* a = act + C_LOFFP[lvl] + (size_t)n * C_HWP[lvl] * 256;

    int px[2]; size_t aoff[2];
#pragma unroll
    for (int j = 0; j < 2; j++) {
        px[j] = p0 + wid * 32 + j * 16 + l16;
        int lpx = px[j] < HW ? px[j] : 0;
        int y = lpx >> lw, x = lpx & (W - 1);
        aoff[j] = (size_t)((y + 1) * Wp + x + 1) * 256;
    }

    f32x4 acc[5][2];
#pragma unroll
    for (int mf = 0; mf < 5; mf++) { acc[mf][0] = (f32x4){0,0,0,0}; acc[mf][1] = (f32x4){0,0,0,0}; }

    for (int cc = 0; cc < 256; cc += 32) {
        short8 b0 = *(const short8*)(a + aoff[0] + cc + quad * 8);
        short8 b1 = *(const short8*)(a + aoff[1] + cc + quad * 8);
#pragma unroll
        for (int mf = 0; mf < 5; mf++) {
            short8 av = *(const short8*)(w + (mf * 16 + l16) * 256 + cc + quad * 8);
            acc[mf][0] = __builtin_amdgcn_mfma_f32_16x16x32_bf16(av, b0, acc[mf][0], 0, 0, 0);
            acc[mf][1] = __builtin_amdgcn_mfma_f32_16x16x32_bf16(av, b1, acc[mf][1], 0, 0, 0);
        }
    }

    float* ob = out + C_CLSO[lvl] + (size_t)n * 80 * HW;
#pragma unroll
    for (int mf = 0; mf < 5; mf++) {
        const int co0 = mf * 16 + quad * 4;
#pragma unroll
        for (int j = 0; j < 2; j++) {
            if (px[j] < HW) {
#pragma unroll
                for (int r = 0; r < 4; r++)
                    ob[(size_t)(co0 + r) * HW + px[j]] = acc[mf][j][r] + bias[co0 + r];
            }
        }
    }
}

// ---------------------------------------------------------------------------
// final 1x1 reg: 256 -> 5 + bias; ch0 centerness, ch1..4 max(raw*stride,0).
// ---------------------------------------------------------------------------
__global__ __launch_bounds__(256) void final_reg(
    const unsigned short* __restrict__ act, const float* __restrict__ w,
    const float* __restrict__ bias, float* __restrict__ out)
{
    const int lvl = blockIdx.y, n = blockIdx.z;
    const int HW = C_HW[lvl];
    const int W = C_W[lvl], lw = C_LW[lvl], Wp = C_WP[lvl];
    const int tid = threadIdx.x;

    __shared__ float ws[5 * 256];
    for (int idx = tid; idx < 5 * 256; idx += 256) ws[idx] = w[idx];
    __syncthreads();

    const int px = blockIdx.x * 256 + tid;
    if (px >= HW) return;

    const int y = px >> lw, x = px & (W - 1);
    const unsigned short* a = act + C_LOFFP[lvl] + (size_t)n * C_HWP[lvl] * 256
                            + (size_t)((y + 1) * Wp + x + 1) * 256;
    float acc[5] = {0.f, 0.f, 0.f, 0.f, 0.f};

    for (int ci = 0; ci < 256; ci += 8) {
        ushort4 u0 = *(const ushort4*)(a + ci);
        ushort4 u1 = *(const ushort4*)(a + ci + 4);
        float xv[8] = {bf2f(u0.x), bf2f(u0.y), bf2f(u0.z), bf2f(u0.w),
                       bf2f(u1.x), bf2f(u1.y), bf2f(u1.z), bf2f(u1.w)};
#pragma unroll
        for (int j = 0; j < 5; j++) {
            const float* wj = &ws[j * 256 + ci];
#pragma unroll
            for (int k = 0; k < 8; k++) acc[j] = fmaf(xv[k], wj[k], acc[j]);
        }
    }

    const float strf = C_STRF[lvl];
    out[C_CENTO[lvl] + (size_t)n * HW + px] = acc[0] + bias[0];
    float* rb = out + C_REGO[lvl] + (size_t)n * 4 * HW;
#pragma unroll
    for (int j = 0; j < 4; j++)
        rb[(size_t)j * HW + px] = fmaxf((acc[j + 1] + bias[j + 1]) * strf, 0.f);
}

// ---------------------------------------------------------------------------
extern "C" void kernel_launch(void* const* d_in, const int* in_sizes, int n_in,
                              void* d_out, int out_size, void* d_ws, size_t ws_size,
                              hipStream_t stream)
{
    const float* cls_w  = (const float*)d_in[5];
    const float* cls_s  = (const float*)d_in[6];
    const float* cls_b  = (const float*)d_in[7];
    const float* cls_fw = (const float*)d_in[8];
    const float* cls_fb = (const float*)d_in[9];
    const float* reg_w  = (const float*)d_in[10];
    const float* reg_s  = (const float*)d_in[11];
    const float* reg_b  = (const float*)d_in[12];
    const float* reg_fw = (const float*)d_in[13];
    const float* reg_fb = (const float*)d_in[14];
    float* out = (float*)d_out;

    unsigned short *actC, *actA0, *actB0, *actA1, *actB1, *wc, *wr, *w1c;
    hipGetSymbolAddress((void**)&actC,  HIP_SYMBOL(g_actC));
    hipGetSymbolAddress((void**)&actA0, HIP_SYMBOL(g_actA0));
    hipGetSymbolAddress((void**)&actB0, HIP_SYMBOL(g_actB0));
    hipGetSymbolAddress((void**)&actA1, HIP_SYMBOL(g_actA1));
    hipGetSymbolAddress((void**)&actB1, HIP_SYMBOL(g_actB1));
    hipGetSymbolAddress((void**)&wc,    HIP_SYMBOL(g_wc));
    hipGetSymbolAddress((void**)&wr,    HIP_SYMBOL(g_wr));
    hipGetSymbolAddress((void**)&w1c,   HIP_SYMBOL(g_w1c));

    cvt_w3<<<dim3(256, 36, 2), 256, 0, stream>>>(cls_w, reg_w, wc, wr);
    cvt_w1<<<1, 256, 0, stream>>>(cls_fw, w1c);
    zero_halo<<<100, 256, 0, stream>>>(actC, actA0, actB0, actA1, actB1);
    cvt_in<<<dim3(256, 5, 4), 256, 0, stream>>>(
        (const float*)d_in[0], (const float*)d_in[1], (const float*)d_in[2],
        (const float*)d_in[3], (const float*)d_in[4], actC);

    unsigned short* srcs[4][2] = {{actC, actC}, {actA0, actA1}, {actB0, actB1}, {actA0, actA1}};
    unsigned short* dsts[4][2] = {{actA0, actA1}, {actB0, actB1}, {actA0, actA1}, {actB0, actB1}};
    for (int s = 0; s < 4; s++) {
        conv3x3_mfma<<<dim3(171, 1, 8), 512, 0, stream>>>(
            srcs[s][0], srcs[s][1], dsts[s][0], dsts[s][1],
            wc + (size_t)s * WSTEP, wr + (size_t)s * WSTEP,
            cls_s + s * 256, cls_b + s * 256, reg_s + s * 256, reg_b + s * 256);
    }

    final_cls<<<dim3(128, 5, 4), 256, 0, stream>>>(actB0, w1c, cls_fb, out);
    final_reg<<<dim3(64, 5, 4), 256, 0, stream>>>(actB1, reg_fw, reg_fb, out);
}